// Round 2
// baseline (808.691 us; speedup 1.0000x reference)
//
#include <hip/hip_runtime.h>
#include <hip/hip_bf16.h>
#include <stdint.h>

#define T_TOK 8192
#define D_DIM 1024
#define H_DIM 2048
#define E_NUM 8
#define KSEL  2
#define NROWS (T_TOK*KSEL)

#define BM 128
#define BN 128
#define BK 64

typedef __bf16 bf16_t;
typedef bf16_t bf16x8 __attribute__((ext_vector_type(8)));
typedef float  f32x4  __attribute__((ext_vector_type(4)));

__device__ __forceinline__ ushort f2bf(float f) {
    uint32_t u = __builtin_bit_cast(uint32_t, f);
    uint32_t r = (u + 0x7FFFu + ((u >> 16) & 1u)) >> 16;   // RNE
    return (ushort)r;
}

// ---------------- fp32 -> bf16 bulk convert (weights) ----------------
__global__ __launch_bounds__(256) void convert_kernel(const float* __restrict__ src,
                                                      ushort* __restrict__ dst, int n4) {
    int i = blockIdx.x * 256 + threadIdx.x;
    int stride = gridDim.x * 256;
    for (; i < n4; i += stride) {
        float4 v = *(const float4*)(src + (size_t)i * 4);
        ushort4 o;
        o.x = f2bf(v.x); o.y = f2bf(v.y); o.z = f2bf(v.z); o.w = f2bf(v.w);
        *(ushort4*)(dst + (size_t)i * 4) = o;
    }
}

// ---------------- router: logits, softmax-top2, x->bf16 ----------------
__global__ __launch_bounds__(256) void router_kernel(const float* __restrict__ x,
                                                     const float* __restrict__ rw,
                                                     ushort* __restrict__ x16,
                                                     int* __restrict__ topk_idx,
                                                     float* __restrict__ topk_w,
                                                     int* __restrict__ cnt) {
    const int wid  = threadIdx.x >> 6;
    const int lane = threadIdx.x & 63;
    const int t = blockIdx.x * 4 + wid;
    const float* xr = x + (size_t)t * D_DIM;

    float acc[E_NUM];
#pragma unroll
    for (int e = 0; e < E_NUM; e++) acc[e] = 0.f;

#pragma unroll
    for (int i = 0; i < 4; i++) {
        int d0 = i * 256 + lane * 4;
        float4 xv = *(const float4*)(xr + d0);
        ushort4 o;
        o.x = f2bf(xv.x); o.y = f2bf(xv.y); o.z = f2bf(xv.z); o.w = f2bf(xv.w);
        *(ushort4*)(x16 + (size_t)t * D_DIM + d0) = o;
#pragma unroll
        for (int e = 0; e < E_NUM; e++) {
            float4 wv = *(const float4*)(rw + e * D_DIM + d0);
            acc[e] += xv.x * wv.x + xv.y * wv.y + xv.z * wv.z + xv.w * wv.w;
        }
    }
#pragma unroll
    for (int e = 0; e < E_NUM; e++) {
#pragma unroll
        for (int s = 32; s > 0; s >>= 1) acc[e] += __shfl_xor(acc[e], s);
    }
    // top-2 (strict > keeps lowest index on tie, matching lax.top_k)
    int e1 = 0; float m1 = acc[0];
#pragma unroll
    for (int e = 1; e < E_NUM; e++) if (acc[e] > m1) { m1 = acc[e]; e1 = e; }
    int e2 = -1; float m2 = -INFINITY;
#pragma unroll
    for (int e = 0; e < E_NUM; e++) if (e != e1 && acc[e] > m2) { m2 = acc[e]; e2 = e; }
    float w1 = 1.f / (1.f + expf(m2 - m1));   // == p1/(p1+p2)
    float w2 = 1.f - w1;
    if (lane == 0) {
        topk_idx[t * 2 + 0] = e1; topk_idx[t * 2 + 1] = e2;
        topk_w  [t * 2 + 0] = w1; topk_w  [t * 2 + 1] = w2;
        atomicAdd(cnt + e1, 1);
        atomicAdd(cnt + e2, 1);
    }
}

// ---------------- tiny prefix sum over 8 experts ----------------
__global__ void prefix_kernel(const int* __restrict__ cnt, int* __restrict__ offs,
                              int* __restrict__ fill) {
    if (threadIdx.x == 0) {
        int s = 0;
        for (int e = 0; e < E_NUM; e++) { offs[e] = s; fill[e] = s; s += cnt[e]; }
        offs[E_NUM] = s;
    }
}

// ---------------- scatter tokens to compacted per-expert rows ----------------
__global__ __launch_bounds__(256) void scatter_kernel(const int* __restrict__ topk_idx,
                                                      const float* __restrict__ topk_w,
                                                      int* __restrict__ fill,
                                                      int* __restrict__ row_token,
                                                      float* __restrict__ row_weight) {
    int t = blockIdx.x * 256 + threadIdx.x;
#pragma unroll
    for (int k = 0; k < KSEL; k++) {
        int e = topk_idx[t * 2 + k];
        float w = topk_w[t * 2 + k];
        int pos = atomicAdd(fill + e, 1);
        row_token[pos] = t;
        row_weight[pos] = w;
    }
}

// ---------------- grouped GEMM: gate+up fused, SiLU epilogue ----------------
__global__ __launch_bounds__(512) void gateup_kernel(const ushort* __restrict__ x16,
                                                     const ushort* __restrict__ wg16,
                                                     const ushort* __restrict__ wu16,
                                                     const int* __restrict__ offs,
                                                     const int* __restrict__ row_token,
                                                     ushort* __restrict__ h16) {
    const int e = blockIdx.z;
    const int off_e = offs[e];
    const int n_e = offs[e + 1] - off_e;
    const int m0 = blockIdx.y * BM;
    if (m0 >= n_e) return;            // uniform across block: safe
    const int n0 = blockIdx.x * BN;

    __shared__ __align__(16) ushort sA[BM * BK];
    __shared__ __align__(16) ushort sBg[BN * BK];
    __shared__ __align__(16) ushort sBu[BN * BK];
    __shared__ int sTok[BM];

    const int tid = threadIdx.x;
    if (tid < BM) {
        int r = m0 + tid;
        sTok[tid] = row_token[off_e + (r < n_e ? r : n_e - 1)];
    }
    __syncthreads();

    const int srow = tid >> 2;
    const int sq   = tid & 3;
    const int swz  = srow & 7;
    const int c0 = ((2 * sq)     ^ swz) * 8;
    const int c1 = ((2 * sq + 1) ^ swz) * 8;
    ushort* sAw  = &sA [srow * BK];
    ushort* sBgw = &sBg[srow * BK];
    ushort* sBuw = &sBu[srow * BK];

    const ushort* aRow = x16 + (size_t)sTok[srow] * D_DIM + sq * 16;
    const ushort* gRow = wg16 + ((size_t)e * H_DIM + (n0 + srow)) * D_DIM + sq * 16;
    const ushort* uRow = wu16 + ((size_t)e * H_DIM + (n0 + srow)) * D_DIM + sq * 16;

    const int wid = tid >> 6, lane = tid & 63;
    const int wr = wid >> 2, wc = wid & 3;        // 2x4 wave grid, 64x32 per wave
    const int fr = lane & 15, fq = lane >> 4;

    f32x4 accg[4][2], accu[4][2];
    f32x4 z4 = {0.f, 0.f, 0.f, 0.f};
#pragma unroll
    for (int m = 0; m < 4; m++)
#pragma unroll
        for (int n = 0; n < 2; n++) { accg[m][n] = z4; accu[m][n] = z4; }

    uint4 ra0 = *(const uint4*)(aRow);
    uint4 ra1 = *(const uint4*)(aRow + 8);
    uint4 rg0 = *(const uint4*)(gRow);
    uint4 rg1 = *(const uint4*)(gRow + 8);
    uint4 ru0 = *(const uint4*)(uRow);
    uint4 ru1 = *(const uint4*)(uRow + 8);

    const int NKT = D_DIM / BK;   // 16
    for (int kt = 0; kt < NKT; ++kt) {
        *(uint4*)&sAw [c0] = ra0; *(uint4*)&sAw [c1] = ra1;
        *(uint4*)&sBgw[c0] = rg0; *(uint4*)&sBgw[c1] = rg1;
        *(uint4*)&sBuw[c0] = ru0; *(uint4*)&sBuw[c1] = ru1;
        if (kt + 1 < NKT) {                 // prefetch next K-tile into regs
            const ushort* a = aRow + (kt + 1) * BK;
            const ushort* g = gRow + (kt + 1) * BK;
            const ushort* u = uRow + (kt + 1) * BK;
            ra0 = *(const uint4*)(a); ra1 = *(const uint4*)(a + 8);
            rg0 = *(const uint4*)(g); rg1 = *(const uint4*)(g + 8);
            ru0 = *(const uint4*)(u); ru1 = *(const uint4*)(u + 8);
        }
        __syncthreads();
#pragma unroll
        for (int ks = 0; ks < 2; ++ks) {
            bf16x8 af[4], bg[2], bu[2];
#pragma unroll
            for (int m = 0; m < 4; m++) {
                int r = wr * 64 + m * 16 + fr;
                af[m] = *(const bf16x8*)&sA[r * BK + (((ks * 4 + fq) ^ (r & 7)) * 8)];
            }
#pragma unroll
            for (int n = 0; n < 2; n++) {
                int c = wc * 32 + n * 16 + fr;
                int sl = ((ks * 4 + fq) ^ (c & 7)) * 8;
                bg[n] = *(const bf16x8*)&sBg[c * BK + sl];
                bu[n] = *(const bf16x8*)&sBu[c * BK + sl];
            }
#pragma unroll
            for (int m = 0; m < 4; m++)
#pragma unroll
                for (int n = 0; n < 2; n++) {
                    accg[m][n] = __builtin_amdgcn_mfma_f32_16x16x32_bf16(af[m], bg[n], accg[m][n], 0, 0, 0);
                    accu[m][n] = __builtin_amdgcn_mfma_f32_16x16x32_bf16(af[m], bu[n], accu[m][n], 0, 0, 0);
                }
        }
        __syncthreads();
    }

#pragma unroll
    for (int m = 0; m < 4; m++)
#pragma unroll
        for (int n = 0; n < 2; n++) {
            int col = n0 + wc * 32 + n * 16 + fr;
#pragma unroll
            for (int v = 0; v < 4; v++) {
                int grow = m0 + wr * 64 + m * 16 + fq * 4 + v;
                if (grow < n_e) {
                    float g = accg[m][n][v], u = accu[m][n][v];
                    float h = g / (1.f + expf(-g)) * u;
                    h16[(size_t)(off_e + grow) * H_DIM + col] = f2bf(h);
                }
            }
        }
}

// ---------------- grouped GEMM: down proj, weighted atomic scatter ----------------
__global__ __launch_bounds__(512) void down_kernel(const ushort* __restrict__ h16,
                                                   const ushort* __restrict__ wd16,
                                                   const int* __restrict__ offs,
                                                   const int* __restrict__ row_token,
                                                   const float* __restrict__ row_weight,
                                                   float* __restrict__ out) {
    const int e = blockIdx.z;
    const int off_e = offs[e];
    const int n_e = offs[e + 1] - off_e;
    const int m0 = blockIdx.y * BM;
    if (m0 >= n_e) return;
    const int n0 = blockIdx.x * BN;

    __shared__ __align__(16) ushort sA[BM * BK];
    __shared__ __align__(16) ushort sB[BN * BK];

    const int tid = threadIdx.x;
    const int srow = tid >> 2;
    const int sq   = tid & 3;
    const int swz  = srow & 7;
    const int c0 = ((2 * sq)     ^ swz) * 8;
    const int c1 = ((2 * sq + 1) ^ swz) * 8;
    ushort* sAw = &sA[srow * BK];
    ushort* sBw = &sB[srow * BK];

    int arow = m0 + srow; if (arow >= n_e) arow = n_e - 1;
    const ushort* aRow = h16 + (size_t)(off_e + arow) * H_DIM + sq * 16;
    const ushort* bRow = wd16 + ((size_t)e * D_DIM + (n0 + srow)) * H_DIM + sq * 16;

    const int wid = tid >> 6, lane = tid & 63;
    const int wr = wid >> 2, wc = wid & 3;
    const int fr = lane & 15, fq = lane >> 4;

    f32x4 acc[4][2];
    f32x4 z4 = {0.f, 0.f, 0.f, 0.f};
#pragma unroll
    for (int m = 0; m < 4; m++)
#pragma unroll
        for (int n = 0; n < 2; n++) acc[m][n] = z4;

    uint4 ra0 = *(const uint4*)(aRow);
    uint4 ra1 = *(const uint4*)(aRow + 8);
    uint4 rb0 = *(const uint4*)(bRow);
    uint4 rb1 = *(const uint4*)(bRow + 8);

    const int NKT = H_DIM / BK;   // 32
    for (int kt = 0; kt < NKT; ++kt) {
        *(uint4*)&sAw[c0] = ra0; *(uint4*)&sAw[c1] = ra1;
        *(uint4*)&sBw[c0] = rb0; *(uint4*)&sBw[c1] = rb1;
        if (kt + 1 < NKT) {
            const ushort* a = aRow + (kt + 1) * BK;
            const ushort* b = bRow + (kt + 1) * BK;
            ra0 = *(const uint4*)(a); ra1 = *(const uint4*)(a + 8);
            rb0 = *(const uint4*)(b); rb1 = *(const uint4*)(b + 8);
        }
        __syncthreads();
#pragma unroll
        for (int ks = 0; ks < 2; ++ks) {
            bf16x8 af[4], bf[2];
#pragma unroll
            for (int m = 0; m < 4; m++) {
                int r = wr * 64 + m * 16 + fr;
                af[m] = *(const bf16x8*)&sA[r * BK + (((ks * 4 + fq) ^ (r & 7)) * 8)];
            }
#pragma unroll
            for (int n = 0; n < 2; n++) {
                int c = wc * 32 + n * 16 + fr;
                bf[n] = *(const bf16x8*)&sB[c * BK + (((ks * 4 + fq) ^ (c & 7)) * 8)];
            }
#pragma unroll
            for (int m = 0; m < 4; m++)
#pragma unroll
                for (int n = 0; n < 2; n++)
                    acc[m][n] = __builtin_amdgcn_mfma_f32_16x16x32_bf16(af[m], bf[n], acc[m][n], 0, 0, 0);
        }
        __syncthreads();
    }

#pragma unroll
    for (int m = 0; m < 4; m++)
#pragma unroll
        for (int n = 0; n < 2; n++) {
            int col = n0 + wc * 32 + n * 16 + fr;
#pragma unroll
            for (int v = 0; v < 4; v++) {
                int grow = m0 + wr * 64 + m * 16 + fq * 4 + v;
                if (grow < n_e) {
                    int r = off_e + grow;
                    float w = row_weight[r];
                    int tok = row_token[r];
                    atomicAdd(out + (size_t)tok * D_DIM + col, w * acc[m][n][v]);
                }
            }
        }
}

extern "C" void kernel_launch(void* const* d_in, const int* in_sizes, int n_in,
                              void* d_out, int out_size, void* d_ws, size_t ws_size,
                              hipStream_t stream) {
    const float* x  = (const float*)d_in[0];
    const float* rw = (const float*)d_in[1];
    const float* wg = (const float*)d_in[2];
    const float* wu = (const float*)d_in[3];
    const float* wd = (const float*)d_in[4];
    float* out = (float*)d_out;

    char* p = (char*)d_ws;
    size_t off = 0;
    auto alloc = [&](size_t b) { size_t c = off; off = (off + b + 255) & ~(size_t)255; return c; };
    size_t ctrl_o = alloc(256);
    size_t tki_o  = alloc((size_t)T_TOK * KSEL * 4);
    size_t tkw_o  = alloc((size_t)T_TOK * KSEL * 4);
    size_t rtok_o = alloc((size_t)NROWS * 4);
    size_t rwgt_o = alloc((size_t)NROWS * 4);
    size_t x16_o  = alloc((size_t)T_TOK * D_DIM * 2);
    size_t wg16_o = alloc((size_t)E_NUM * H_DIM * D_DIM * 2);
    size_t wu16_o = alloc((size_t)E_NUM * H_DIM * D_DIM * 2);
    size_t wd16_o = alloc((size_t)E_NUM * D_DIM * H_DIM * 2);
    size_t h16_o  = alloc((size_t)NROWS * H_DIM * 2);
    if (off > ws_size) return;   // insufficient workspace -> visible failure

    int*    cnt        = (int*)(p + ctrl_o);           // 8 ints
    int*    offs       = (int*)(p + ctrl_o + 64);      // 9 ints
    int*    fill       = (int*)(p + ctrl_o + 128);     // 8 ints
    int*    topk_idx   = (int*)(p + tki_o);
    float*  topk_w     = (float*)(p + tkw_o);
    int*    row_token  = (int*)(p + rtok_o);
    float*  row_weight = (float*)(p + rwgt_o);
    ushort* x16  = (ushort*)(p + x16_o);
    ushort* wg16 = (ushort*)(p + wg16_o);
    ushort* wu16 = (ushort*)(p + wu16_o);
    ushort* wd16 = (ushort*)(p + wd16_o);
    ushort* h16  = (ushort*)(p + h16_o);

    hipMemsetAsync(p + ctrl_o, 0, 256, stream);
    hipMemsetAsync(d_out, 0, (size_t)out_size * 4, stream);

    const int n4w = (E_NUM * H_DIM * D_DIM) / 4;
    convert_kernel<<<1024, 256, 0, stream>>>(wg, wg16, n4w);
    convert_kernel<<<1024, 256, 0, stream>>>(wu, wu16, n4w);
    convert_kernel<<<1024, 256, 0, stream>>>(wd, wd16, n4w);

    router_kernel<<<T_TOK / 4, 256, 0, stream>>>(x, rw, x16, topk_idx, topk_w, cnt);
    prefix_kernel<<<1, 64, 0, stream>>>(cnt, offs, fill);
    scatter_kernel<<<T_TOK / 256, 256, 0, stream>>>(topk_idx, topk_w, fill, row_token, row_weight);

    gateup_kernel<<<dim3(H_DIM / BN, T_TOK / BM, E_NUM), 512, 0, stream>>>(
        x16, wg16, wu16, offs, row_token, h16);
    down_kernel<<<dim3(D_DIM / BN, T_TOK / BM, E_NUM), 512, 0, stream>>>(
        h16, wd16, offs, row_token, row_weight, out);
}